// Round 10
// baseline (229.467 us; speedup 1.0000x reference)
//
#include <hip/hip_runtime.h>

#define HEADS 16
#define DH    64
#define EMB   1024
#define NBAT  2
#define SEQ   2048
#define KDIM  1024
#define NROW  (NBAT * SEQ)     // 4096 rows in projection GEMM

typedef __attribute__((ext_vector_type(8))) short short8;   // 8 bf16 MFMA A/B frag
typedef __attribute__((ext_vector_type(4))) short short4v;  // 4 bf16 (8B packed store)
typedef __attribute__((ext_vector_type(4))) float floatx4;  // MFMA C/D frag
typedef unsigned short u16;
typedef unsigned int   u32;
typedef unsigned long long u64;

__device__ __forceinline__ u16 f2bf(float x) {          // fp32 -> bf16 RNE
    u32 u = __builtin_bit_cast(u32, x);
    u += 0x7fffu + ((u >> 16) & 1u);
    return (u16)(u >> 16);
}
__device__ __forceinline__ float bf2f(u16 v) {
    return __builtin_bit_cast(float, ((u32)v) << 16);
}

// async global->LDS, 16B per lane; LDS dest is wave-uniform base + lane*16
__device__ __forceinline__ void gll16(const u16* g, u16* l) {
    __builtin_amdgcn_global_load_lds((const __attribute__((address_space(1))) u32*)g,
                                     (__attribute__((address_space(3))) u32*)l, 16, 0, 0);
}

// ---------------------------------------------------------------------------
// fp32 -> bf16 pre-convert of X (q,k,v: 4M elems each) and W (wq,wk,wv: 1M each)
// ---------------------------------------------------------------------------
__global__ __launch_bounds__(256) void cvt_kernel(
    const float* __restrict__ q, const float* __restrict__ k, const float* __restrict__ v,
    const float* __restrict__ wq, const float* __restrict__ wk, const float* __restrict__ wv,
    u16* __restrict__ xb, u16* __restrict__ wb)
{
    const int z = blockIdx.y;
    const float* src; u16* dst; int n;
    if (z < 3) { src = (z == 0) ? q : (z == 1) ? k : v;     dst = xb + (size_t)z * 4194304;       n = 4194304; }
    else       { src = (z == 3) ? wq : (z == 4) ? wk : wv;  dst = wb + (size_t)(z - 3) * 1048576; n = 1048576; }
    for (int i = (blockIdx.x * 256 + threadIdx.x) * 8; i < n; i += 512 * 256 * 8) {
        float4 a = *(const float4*)(src + i);
        float4 b = *(const float4*)(src + i + 4);
        short8 o;
        o[0] = (short)f2bf(a.x); o[1] = (short)f2bf(a.y); o[2] = (short)f2bf(a.z); o[3] = (short)f2bf(a.w);
        o[4] = (short)f2bf(b.x); o[5] = (short)f2bf(b.y); o[6] = (short)f2bf(b.z); o[7] = (short)f2bf(b.w);
        *(short8*)(dst + i) = o;
    }
}

// ---------------------------------------------------------------------------
// bf16 GEMM: out = Xb @ Wb^T (+bias). 128x128 tile, BK=64, global_load_lds,
// XOR-swizzled LDS; XCD-swizzled grid 768. z=0: Q*(0.125*log2e) -> qh;
// z=1: K -> kh[n][h][t][d]; z=2: V -> vt[n][h][d][t] (LDS-transposed stores).
// ---------------------------------------------------------------------------
__global__ __launch_bounds__(256) void proj_kernel(
    const u16* __restrict__ xb, const u16* __restrict__ wb,
    const float* __restrict__ bq, const float* __restrict__ bk, const float* __restrict__ bv,
    u16* __restrict__ qh, u16* __restrict__ kh, u16* __restrict__ vt)
{
    const int f = blockIdx.x;
    const int xcd = f & 7, jj = f >> 3;          // jj 0..95
    const int g  = xcd * 12 + (jj >> 3);         // row-group 0..95 (z*32+y)
    const int nx = jj & 7;                       // n-tile 0..7
    const int z  = g >> 5, y = g & 31;

    const u16* A  = xb + (size_t)z * 4194304;
    const u16* B  = wb + (size_t)z * 1048576;
    const float* Bp = (z == 0) ? bq : (z == 1) ? bk : bv;
    u16* dst        = (z == 0) ? qh : (z == 1) ? kh : vt;

    const int m0 = y * 128;
    const int n0 = nx * 128;
    const int tid  = threadIdx.x;
    const int wave = tid >> 6, lane = tid & 63;
    const int quad = lane >> 4, l15 = lane & 15;
    const int waveM = wave >> 1, waveN = wave & 1;
    const int sw = l15 & 7;                      // read-side swizzle key (row&7)

    // single array so the epilogue transpose can alias the full 32KB
    __shared__ __align__(16) u16 smem[2 * 128 * 64];
    u16* As = smem;
    u16* Bs = smem + 128 * 64;

    floatx4 acc[4][4];
    for (int a = 0; a < 4; a++)
        for (int b = 0; b < 4; b++)
            acc[a][b] = floatx4{0.f, 0.f, 0.f, 0.f};

    const int lrow = lane >> 3;                  // 0..7 within 8-row slab
    const int gcol = ((lane & 7) ^ lrow) * 8;    // XOR-swizzled source chunk

    for (int k0 = 0; k0 < KDIM; k0 += 64) {
        for (int j = 0; j < 4; j++) {
            int r8 = wave * 32 + j * 8;
            gll16(A + (size_t)(m0 + r8 + lrow) * KDIM + k0 + gcol, &As[r8 * 64]);
        }
        for (int j = 0; j < 4; j++) {
            int r8 = wave * 32 + j * 8;
            gll16(B + (size_t)(n0 + r8 + lrow) * KDIM + k0 + gcol, &Bs[r8 * 64]);
        }
        __syncthreads();

        for (int ks = 0; ks < 2; ks++) {
            short8 af[4], bfg[4];
            for (int mb = 0; mb < 4; mb++)
                af[mb]  = *(const short8*)&As[(waveM * 64 + mb * 16 + l15) * 64 + ((ks * 4 + quad) ^ sw) * 8];
            for (int nb = 0; nb < 4; nb++)
                bfg[nb] = *(const short8*)&Bs[(waveN * 64 + nb * 16 + l15) * 64 + ((ks * 4 + quad) ^ sw) * 8];
            for (int mb = 0; mb < 4; mb++)
                for (int nb = 0; nb < 4; nb++)
                    acc[mb][nb] = __builtin_amdgcn_mfma_f32_16x16x32_bf16(af[mb], bfg[nb], acc[mb][nb], 0, 0, 0);
        }
        __syncthreads();
    }

    if (z != 2) {
        // direct stores: [n][h][s][d]; 16 consecutive d per quad = 32B runs
        const int row0 = m0 + waveM * 64;
        const int col0 = n0 + waveN * 64;
        // z=0: fold 1/sqrt(d) * log2(e) so softmax uses bare v_exp_f32 (2^x)
        const float scale = (z == 0) ? 0.125f * 1.44269504f : 1.0f;
        for (int nb = 0; nb < 4; nb++) {
            int col = col0 + nb * 16 + l15;
            float bias = Bp[col];
            int hh = col >> 6, dd = col & 63;
            for (int mb = 0; mb < 4; mb++) {
                for (int r = 0; r < 4; r++) {
                    int row = row0 + mb * 16 + quad * 4 + r;   // C/D: row = quad*4+reg
                    int nn = row >> 11, ss = row & 2047;
                    dst[((size_t)(nn * HEADS + hh) * SEQ + ss) * DH + dd] =
                        f2bf((acc[mb][nb][r] + bias) * scale);
                }
            }
        }
    } else {
        // V^T [n][h][d][t]: transpose 64-col half-tiles through LDS (stride 136
        // u16 -> 2-way bank aliasing = free), then coalesced 16B stores.
        const int nn  = m0 >> 11;
        const int ss0 = m0 & 2047;
        for (int p = 0; p < 2; p++) {
            if (waveN == p) {
                for (int nb = 0; nb < 4; nb++) {
                    int col_l = nb * 16 + l15;                   // d within head, 0..63
                    float bias = Bp[n0 + p * 64 + col_l];
                    for (int mb = 0; mb < 4; mb++) {
                        short4v pk;
                        for (int r = 0; r < 4; r++)
                            pk[r] = (short)f2bf(acc[mb][nb][r] + bias);
                        *(short4v*)&smem[col_l * 136 + waveM * 64 + mb * 16 + quad * 4] = pk;
                    }
                }
            }
            __syncthreads();
            const int hh = (n0 >> 6) + p;
            u16* drow = dst + ((size_t)(nn * HEADS + hh) * DH) * SEQ + ss0;
            for (int c2 = tid; c2 < 1024; c2 += 256) {
                int dl = c2 >> 4, tc = (c2 & 15) * 8;
                short8 vv = *(const short8*)&smem[dl * 136 + tc];
                *(short8*)(drow + (size_t)dl * SEQ + tc) = vv;
            }
            __syncthreads();
        }
    }
}

// ---------------------------------------------------------------------------
// vmean[(n*H+h)*D + d] = mean over t of projected V (fallback for fully-masked rows)
// ---------------------------------------------------------------------------
__global__ __launch_bounds__(256) void vmean_kernel(const u16* __restrict__ vt,
                                                    float* __restrict__ vmean)
{
    const int row = blockIdx.x;                // (n*H + h)*D + d
    const u16* p = vt + (size_t)row * SEQ;
    const int tid = threadIdx.x;
    float s = 0.f;
    for (int i = tid; i < SEQ; i += 256) s += bf2f(p[i]);
    __shared__ float red[256];
    red[tid] = s;
    __syncthreads();
    for (int st = 128; st > 0; st >>= 1) {
        if (tid < st) red[tid] += red[tid + st];
        __syncthreads();
    }
    if (tid == 0) vmean[row] = red[0] * (1.f / (float)SEQ);
}

// ---------------------------------------------------------------------------
// Attention v4: DUAL-Q-TILE single K/V stream. (R3 unroll reverted: measured
// +10us, VALU cycles UP -> address-recompute theory falsified. R1/R7 counters
// => latency-bound serial QK->SM->PV chain, 2 waves/SIMD, barrier-locked.)
// Block owns pair (A=pr short, B=31-pr long). Phase 1 (tb=0..pr): BOTH tiles
// per iteration -- K/V frag loads shared (1 ds_read feeds 2 MFMAs), two
// independent MFMA/exp2 chains per wave fill the ~43% idle; one staging+
// barrier serves both tiles. Phase 2 (tb=pr+1..31-pr): single-tile R1 body.
// Compute per block uniform (33 tile-units for every pr); staging/barriers
// drop 33 -> 32-pr (avg 24.5); attn K/V HBM reads halve. Adjacent blockIdx
// gets complementary pr (long+short pairs per CU). Barrier scheme per
// iteration identical to R1-verified. Softmax: pre-scaled log2e -> bare exp2.
// Pad mask = ballot bitmask; causal only on diagonal tiles; l==0 -> vmean.
// T5: s_setprio(1) around MFMA clusters.
// ---------------------------------------------------------------------------
__global__ __launch_bounds__(256) void attn_kernel(
    const u16* __restrict__ qh, const u16* __restrict__ kh, const u16* __restrict__ vt,
    const int* __restrict__ pad, const float* __restrict__ vmean,
    float* __restrict__ out)
{
    const int f = blockIdx.x;
    const int xcd = f & 7, jj = f >> 3;        // jj 0..63
    const int nh = xcd * 4 + (jj >> 4);
    const int idx = jj & 15;
    // complementary adjacent ordering: 0,15,1,14,... so neighbor blocks pair
    // a long stream with a short one on the same CU
    const int pr = (idx & 1) ? (15 - (idx >> 1)) : (idx >> 1);
    const int n = nh >> 4, h = nh & 15;
    const int tid  = threadIdx.x;
    const int wave = tid >> 6, lane = tid & 63;
    const int quad = lane >> 4, l15 = lane & 15;
    const int sw = l15 & 7;                    // frag-read swizzle key

    __shared__ __align__(16) u16 Ks[2][64 * 64];   // [t][d], XOR-swizzled chunks
    __shared__ __align__(16) u16 Vs[2][64 * 64];   // [d][t], XOR-swizzled chunks
    __shared__ __align__(16) u16 Ps[128 * 72];     // P rows: A=0..63, B=64..127
    __shared__ u64 padb[32];

    // pad bitmask via wave ballots
    {
        const int* pp = pad + n * SEQ;
        for (int i = 0; i < 8; i++) {
            int seg = wave * 8 + i;
            u64 m = __ballot(pp[seg * 64 + lane] != 0);
            if (lane == 0) padb[seg] = m;
        }
    }

    const u16* qbase = qh + (size_t)nh * SEQ * DH;
    const u16* kbase = kh + (size_t)nh * SEQ * DH;
    const u16* vbase = vt + (size_t)nh * DH * SEQ;

    short8 ones;
    for (int i = 0; i < 8; i++) ones[i] = (short)0x3F80;   // bf16(1.0)
    float vm[4];
    for (int nd = 0; nd < 4; nd++) vm[nd] = vmean[nh * DH + nd * 16 + l15];

    const int lrow = lane >> 3;                 // 0..7 within 8-row slab
    const int gcol = ((lane & 7) ^ lrow) * 8;   // XOR-swizzled source chunk

    const int sbA = pr, sbB = 31 - pr;          // sbA < sbB always (pr<=15)
    const int s0A = sbA * 64, s0B = sbB * 64;
    const int srowA = s0A + wave * 16 + l15;
    const int srowB = s0B + wave * 16 + l15;
    const int prow = (wave * 16 + l15) * 72;    // Ps row base (tile A)

    short8 qfA[2], qfB[2];
    for (int ks = 0; ks < 2; ks++) {
        qfA[ks] = *(const short8*)(qbase + (size_t)srowA * DH + ks * 32 + quad * 8);
        qfB[ks] = *(const short8*)(qbase + (size_t)srowB * DH + ks * 32 + quad * 8);
    }

    floatx4 oaccA[4], laccA, oaccB[4], laccB;
    for (int nd = 0; nd < 4; nd++) {
        oaccA[nd] = floatx4{0.f, 0.f, 0.f, 0.f};
        oaccB[nd] = floatx4{0.f, 0.f, 0.f, 0.f};
    }
    laccA = floatx4{0.f, 0.f, 0.f, 0.f};
    laccB = floatx4{0.f, 0.f, 0.f, 0.f};

    __syncthreads();   // padb visible to all waves

    // stage K/V tile 0 into buffer 0 (wave stages rows wave*16..wave*16+15)
    for (int j2 = 0; j2 < 2; j2++) {
        int r8 = wave * 16 + j2 * 8;
        gll16(kbase + (size_t)(r8 + lrow) * DH + gcol, &Ks[0][r8 * 64]);
        gll16(vbase + (size_t)(r8 + lrow) * SEQ + gcol, &Vs[0][r8 * 64]);
    }

    // ---------------- phase 1: tb = 0..sbA, BOTH tiles active ----------------
    for (int tb = 0; tb <= sbA; tb++) {
        const int cur = tb & 1;
        __syncthreads();       // drains own gll16s (issued a full iter ago) + buffer reuse

        {   // prefetch next tile (tb+1 <= sbA+1 <= sbB always valid here)
            const int t0n = (tb + 1) * 64;
            for (int j2 = 0; j2 < 2; j2++) {
                int r8 = wave * 16 + j2 * 8;
                gll16(kbase + (size_t)(t0n + r8 + lrow) * DH + gcol, &Ks[1 - cur][r8 * 64]);
                gll16(vbase + (size_t)(r8 + lrow) * SEQ + t0n + gcol, &Vs[1 - cur][r8 * 64]);
            }
        }

        const int t0 = tb * 64;
        const u64 w = padb[tb];
        const bool diagA = (tb == sbA);        // B never diagonal in phase 1

        floatx4 scA[4], scB[4];
        for (int nb = 0; nb < 4; nb++) {
            scA[nb] = floatx4{0.f, 0.f, 0.f, 0.f};
            scB[nb] = floatx4{0.f, 0.f, 0.f, 0.f};
        }
        __builtin_amdgcn_s_setprio(1);
        for (int ks = 0; ks < 2; ks++)
            for (int nb = 0; nb < 4; nb++) {
                short8 kf = *(const short8*)&Ks[cur][(nb * 16 + l15) * 64 + ((ks * 4 + quad) ^ sw) * 8];
                scA[nb] = __builtin_amdgcn_mfma_f32_16x16x32_bf16(kf, qfA[ks], scA[nb], 0, 0, 0);
                scB[nb] = __builtin_amdgcn_mfma_f32_16x16x32_bf16(kf, qfB[ks], scB[nb], 0, 0, 0);
            }
        __builtin_amdgcn_s_setprio(0);

        for (int nb = 0; nb < 4; nb++) {
            const int shb = nb * 16 + quad * 4;
            u32 wq = (u32)(w >> shb) & 0xFu;
            short4v pkA, pkB;
            for (int r = 0; r < 4; r++) {
                bool okb = ((wq >> r) & 1u) != 0;
                bool okA = okb && (!diagA || (t0 + shb + r <= srowA));
                float pA_ = okA ? __builtin_amdgcn_exp2f(scA[nb][r]) : 0.f;
                float pB_ = okb ? __builtin_amdgcn_exp2f(scB[nb][r]) : 0.f;
                pkA[r] = (short)f2bf(pA_);
                pkB[r] = (short)f2bf(pB_);
            }
            *(short4v*)&Ps[prow + shb] = pkA;
            *(short4v*)&Ps[64 * 72 + prow + shb] = pkB;
        }
        asm volatile("s_waitcnt lgkmcnt(0)" ::: "memory");   // wave-local Ps RAW

        __builtin_amdgcn_s_setprio(1);
        for (int ks = 0; ks < 2; ks++) {
            short8 paA = *(const short8*)&Ps[prow + ks * 32 + quad * 8];
            short8 paB = *(const short8*)&Ps[64 * 72 + prow + ks * 32 + quad * 8];
            for (int nd = 0; nd < 4; nd++) {
                short8 vb = *(const short8*)&Vs[cur][(nd * 16 + l15) * 64 + ((ks * 4 + quad) ^ sw) * 8];
                oaccA[nd] = __builtin_amdgcn_mfma_f32_16x16x32_bf16(paA, vb, oaccA[nd], 0, 0, 0);
                oaccB[nd] = __builtin_amdgcn_mfma_f32_16x16x32_bf16(paB, vb, oaccB[nd], 0, 0, 0);
            }
            laccA = __builtin_amdgcn_mfma_f32_16x16x32_bf16(paA, ones, laccA, 0, 0, 0);
            laccB = __builtin_amdgcn_mfma_f32_16x16x32_bf16(paB, ones, laccB, 0, 0, 0);
        }
        __builtin_amdgcn_s_setprio(0);
    }

    // ---------------- phase 2: tb = sbA+1..sbB, tile B only ----------------
    for (int tb = sbA + 1; tb <= sbB; tb++) {
        const int cur = tb & 1;
        __syncthreads();

        if (tb + 1 <= sbB) {
            const int t0n = (tb + 1) * 64;
            for (int j2 = 0; j2 < 2; j2++) {
                int r8 = wave * 16 + j2 * 8;
                gll16(kbase + (size_t)(t0n + r8 + lrow) * DH + gcol, &Ks[1 - cur][r8 * 64]);
                gll16(vbase + (size_t)(r8 + lrow) * SEQ + t0n + gcol, &Vs[1 - cur][r8 * 64]);
            }
        }

        const int t0 = tb * 64;
        const u64 w = padb[tb];
        const bool diagB = (tb == sbB);

        floatx4 scB[4];
        for (int nb = 0; nb < 4; nb++) scB[nb] = floatx4{0.f, 0.f, 0.f, 0.f};
        __builtin_amdgcn_s_setprio(1);
        for (int ks = 0; ks < 2; ks++)
            for (int nb = 0; nb < 4; nb++) {
                short8 kf = *(const short8*)&Ks[cur][(nb * 16 + l15) * 64 + ((ks * 4 + quad) ^ sw) * 8];
                scB[nb] = __builtin_amdgcn_mfma_f32_16x16x32_bf16(kf, qfB[ks], scB[nb], 0, 0, 0);
            }
        __builtin_amdgcn_s_setprio(0);

        for (int nb = 0; nb < 4; nb++) {
            const int shb = nb * 16 + quad * 4;
            u32 wq = (u32)(w >> shb) & 0xFu;
            short4v pkB;
            for (int r = 0; r < 4; r++) {
                bool okb = ((wq >> r) & 1u) != 0;
                if (diagB) okb = okb && (t0 + shb + r <= srowB);
                float pB_ = okb ? __builtin_amdgcn_exp2f(scB[nb][r]) : 0.f;
                pkB[r] = (short)f2bf(pB_);
            }
            *(short4v*)&Ps[64 * 72 + prow + shb] = pkB;
        }
        asm volatile("s_waitcnt lgkmcnt(0)" ::: "memory");

        __builtin_amdgcn_s_setprio(1);
        for (int ks = 0; ks < 2; ks++) {
            short8 paB = *(const short8*)&Ps[64 * 72 + prow + ks * 32 + quad * 8];
            for (int nd = 0; nd < 4; nd++) {
                short8 vb = *(const short8*)&Vs[cur][(nd * 16 + l15) * 64 + ((ks * 4 + quad) ^ sw) * 8];
                oaccB[nd] = __builtin_amdgcn_mfma_f32_16x16x32_bf16(paB, vb, oaccB[nd], 0, 0, 0);
            }
            laccB = __builtin_amdgcn_mfma_f32_16x16x32_bf16(paB, ones, laccB, 0, 0, 0);
        }
        __builtin_amdgcn_s_setprio(0);
    }

    // epilogue: lane holds O[s = s0+wave*16+quad*4+r][d = nd*16+l15]
    for (int r = 0; r < 4; r++) {
        float l = laccA[r];
        int s = s0A + wave * 16 + quad * 4 + r;
        float* orow = out + (size_t)(n * SEQ + s) * EMB + h * DH;
        if (l > 0.f) {
            float inv = 1.f / l;
            for (int nd = 0; nd < 4; nd++) orow[nd * 16 + l15] = oaccA[nd][r] * inv;
        } else {
            for (int nd = 0; nd < 4; nd++) orow[nd * 16 + l15] = vm[nd];
        }
    }
    for (int r = 0; r < 4; r++) {
        float l = laccB[r];
        int s = s0B + wave * 16 + quad * 4 + r;
        float* orow = out + (size_t)(n * SEQ + s) * EMB + h * DH;
        if (l > 0.f) {
            float inv = 1.f / l;
            for (int nd = 0; nd < 4; nd++) orow[nd * 16 + l15] = oaccB[nd][r] * inv;
        } else {
            for (int nd = 0; nd < 4; nd++) orow[nd * 16 + l15] = vm[nd];
        }
    }
}

extern "C" void kernel_launch(void* const* d_in, const int* in_sizes, int n_in,
                              void* d_out, int out_size, void* d_ws, size_t ws_size,
                              hipStream_t stream)
{
    const float* qin = (const float*)d_in[0];
    const float* kin = (const float*)d_in[1];
    const float* vin = (const float*)d_in[2];
    const int*   pad = (const int*)d_in[3];
    // d_in[4] = subsq_mask (tril) — implemented analytically as t <= s
    const float* Wq = (const float*)d_in[5];
    const float* bq = (const float*)d_in[6];
    const float* Wk = (const float*)d_in[7];
    const float* bk = (const float*)d_in[8];
    const float* Wv = (const float*)d_in[9];
    const float* bv = (const float*)d_in[10];
    float* out = (float*)d_out;

    const size_t per = (size_t)NBAT * HEADS * SEQ * DH;  // 4M elements
    u16* qh = (u16*)d_ws;
    u16* kh = qh + per;
    u16* vt = kh + per;
    float* vmean = (float*)(vt + per);                   // 2048 floats
    u16* xb = (u16*)(vmean + 2048);                      // 3 x 4M bf16
    u16* wb = xb + 3 * per;                              // 3 x 1M bf16

    cvt_kernel<<<dim3(512, 6), 256, 0, stream>>>(qin, kin, vin, Wq, Wk, Wv, xb, wb);
    proj_kernel<<<dim3(768), 256, 0, stream>>>(xb, wb, bq, bk, bv, qh, kh, vt);
    vmean_kernel<<<dim3(NBAT * HEADS * DH), 256, 0, stream>>>(vt, vmean);
    attn_kernel<<<dim3(512), 256, 0, stream>>>(qh, kh, vt, pad, vmean, out);
}

// Round 11
// 214.458 us; speedup vs baseline: 1.0700x; 1.0700x over previous
//
#include <hip/hip_runtime.h>

#define HEADS 16
#define DH    64
#define EMB   1024
#define NBAT  2
#define SEQ   2048
#define KDIM  1024
#define NROW  (NBAT * SEQ)     // 4096 rows in projection GEMM

typedef __attribute__((ext_vector_type(8))) short short8;   // 8 bf16 MFMA A/B frag
typedef __attribute__((ext_vector_type(4))) short short4v;  // 4 bf16 (8B packed store)
typedef __attribute__((ext_vector_type(4))) float floatx4;  // MFMA C/D frag
typedef unsigned short u16;
typedef unsigned int   u32;
typedef unsigned long long u64;

__device__ __forceinline__ u16 f2bf(float x) {          // fp32 -> bf16 RNE
    u32 u = __builtin_bit_cast(u32, x);
    u += 0x7fffu + ((u >> 16) & 1u);
    return (u16)(u >> 16);
}
__device__ __forceinline__ float bf2f(u16 v) {
    return __builtin_bit_cast(float, ((u32)v) << 16);
}

// async global->LDS, 16B per lane; LDS dest is wave-uniform base + lane*16
__device__ __forceinline__ void gll16(const u16* g, u16* l) {
    __builtin_amdgcn_global_load_lds((const __attribute__((address_space(1))) u32*)g,
                                     (__attribute__((address_space(3))) u32*)l, 16, 0, 0);
}

// ---------------------------------------------------------------------------
// fp32 -> bf16 pre-convert of X (q,k,v: 4M elems each) and W (wq,wk,wv: 1M each)
// Also zero-inits vmean accumulator (proj z==2 blocks atomicAdd partials).
// ---------------------------------------------------------------------------
__global__ __launch_bounds__(256) void cvt_kernel(
    const float* __restrict__ q, const float* __restrict__ k, const float* __restrict__ v,
    const float* __restrict__ wq, const float* __restrict__ wk, const float* __restrict__ wv,
    u16* __restrict__ xb, u16* __restrict__ wb, float* __restrict__ vmean)
{
    const int z = blockIdx.y;
    if (z == 5 && blockIdx.x == 0) {
        for (int i = threadIdx.x; i < NBAT * HEADS * DH; i += 256) vmean[i] = 0.f;
    }
    const float* src; u16* dst; int n;
    if (z < 3) { src = (z == 0) ? q : (z == 1) ? k : v;     dst = xb + (size_t)z * 4194304;       n = 4194304; }
    else       { src = (z == 3) ? wq : (z == 4) ? wk : wv;  dst = wb + (size_t)(z - 3) * 1048576; n = 1048576; }
    for (int i = (blockIdx.x * 256 + threadIdx.x) * 8; i < n; i += 512 * 256 * 8) {
        float4 a = *(const float4*)(src + i);
        float4 b = *(const float4*)(src + i + 4);
        short8 o;
        o[0] = (short)f2bf(a.x); o[1] = (short)f2bf(a.y); o[2] = (short)f2bf(a.z); o[3] = (short)f2bf(a.w);
        o[4] = (short)f2bf(b.x); o[5] = (short)f2bf(b.y); o[6] = (short)f2bf(b.z); o[7] = (short)f2bf(b.w);
        *(short8*)(dst + i) = o;
    }
}

// ---------------------------------------------------------------------------
// bf16 GEMM: out = Xb @ Wb^T (+bias). 128x128 tile, BK=64, global_load_lds,
// XOR-swizzled LDS; XCD-swizzled grid 768. z=0: Q*(0.125*log2e) -> qh;
// z=1: K -> kh[n][h][t][d]; z=2: V -> vt[n][h][d][t] (LDS-transposed stores)
// + vmean partial sums fused (cross-quad shfl reduce + 1 atomicAdd/col).
// ---------------------------------------------------------------------------
__global__ __launch_bounds__(256) void proj_kernel(
    const u16* __restrict__ xb, const u16* __restrict__ wb,
    const float* __restrict__ bq, const float* __restrict__ bk, const float* __restrict__ bv,
    u16* __restrict__ qh, u16* __restrict__ kh, u16* __restrict__ vt,
    float* __restrict__ vmean)
{
    const int f = blockIdx.x;
    const int xcd = f & 7, jj = f >> 3;          // jj 0..95
    const int g  = xcd * 12 + (jj >> 3);         // row-group 0..95 (z*32+y)
    const int nx = jj & 7;                       // n-tile 0..7
    const int z  = g >> 5, y = g & 31;

    const u16* A  = xb + (size_t)z * 4194304;
    const u16* B  = wb + (size_t)z * 1048576;
    const float* Bp = (z == 0) ? bq : (z == 1) ? bk : bv;
    u16* dst        = (z == 0) ? qh : (z == 1) ? kh : vt;

    const int m0 = y * 128;
    const int n0 = nx * 128;
    const int tid  = threadIdx.x;
    const int wave = tid >> 6, lane = tid & 63;
    const int quad = lane >> 4, l15 = lane & 15;
    const int waveM = wave >> 1, waveN = wave & 1;
    const int sw = l15 & 7;                      // read-side swizzle key (row&7)

    // single array so the epilogue transpose can alias the full 32KB
    __shared__ __align__(16) u16 smem[2 * 128 * 64];
    u16* As = smem;
    u16* Bs = smem + 128 * 64;

    floatx4 acc[4][4];
    for (int a = 0; a < 4; a++)
        for (int b = 0; b < 4; b++)
            acc[a][b] = floatx4{0.f, 0.f, 0.f, 0.f};

    const int lrow = lane >> 3;                  // 0..7 within 8-row slab
    const int gcol = ((lane & 7) ^ lrow) * 8;    // XOR-swizzled source chunk

    for (int k0 = 0; k0 < KDIM; k0 += 64) {
        for (int j = 0; j < 4; j++) {
            int r8 = wave * 32 + j * 8;
            gll16(A + (size_t)(m0 + r8 + lrow) * KDIM + k0 + gcol, &As[r8 * 64]);
        }
        for (int j = 0; j < 4; j++) {
            int r8 = wave * 32 + j * 8;
            gll16(B + (size_t)(n0 + r8 + lrow) * KDIM + k0 + gcol, &Bs[r8 * 64]);
        }
        __syncthreads();

        for (int ks = 0; ks < 2; ks++) {
            short8 af[4], bfg[4];
            for (int mb = 0; mb < 4; mb++)
                af[mb]  = *(const short8*)&As[(waveM * 64 + mb * 16 + l15) * 64 + ((ks * 4 + quad) ^ sw) * 8];
            for (int nb = 0; nb < 4; nb++)
                bfg[nb] = *(const short8*)&Bs[(waveN * 64 + nb * 16 + l15) * 64 + ((ks * 4 + quad) ^ sw) * 8];
            for (int mb = 0; mb < 4; mb++)
                for (int nb = 0; nb < 4; nb++)
                    acc[mb][nb] = __builtin_amdgcn_mfma_f32_16x16x32_bf16(af[mb], bfg[nb], acc[mb][nb], 0, 0, 0);
        }
        __syncthreads();
    }

    if (z != 2) {
        // direct stores: [n][h][s][d]; 16 consecutive d per quad = 32B runs
        const int row0 = m0 + waveM * 64;
        const int col0 = n0 + waveN * 64;
        // z=0: fold 1/sqrt(d) * log2(e) so softmax uses bare v_exp_f32 (2^x)
        const float scale = (z == 0) ? 0.125f * 1.44269504f : 1.0f;
        for (int nb = 0; nb < 4; nb++) {
            int col = col0 + nb * 16 + l15;
            float bias = Bp[col];
            int hh = col >> 6, dd = col & 63;
            for (int mb = 0; mb < 4; mb++) {
                for (int r = 0; r < 4; r++) {
                    int row = row0 + mb * 16 + quad * 4 + r;   // C/D: row = quad*4+reg
                    int nn = row >> 11, ss = row & 2047;
                    dst[((size_t)(nn * HEADS + hh) * SEQ + ss) * DH + dd] =
                        f2bf((acc[mb][nb][r] + bias) * scale);
                }
            }
        }
    } else {
        // V^T [n][h][d][t]: transpose 64-col half-tiles through LDS (stride 136
        // u16 -> 2-way bank aliasing = free), then coalesced 16B stores.
        // Fused vmean partials: psum[nb] = sum over this lane's 16 t-rows of
        // (acc+bias); xor-16/32 shfl reduce over quad -> 64-row partial;
        // one atomicAdd per col per wave. attn divides by SEQ.
        const int nn  = m0 >> 11;
        const int ss0 = m0 & 2047;
        for (int p = 0; p < 2; p++) {
            if (waveN == p) {
                float psum[4] = {0.f, 0.f, 0.f, 0.f};
                for (int nb = 0; nb < 4; nb++) {
                    int col_l = nb * 16 + l15;                   // d within head, 0..63
                    float bias = Bp[n0 + p * 64 + col_l];
                    for (int mb = 0; mb < 4; mb++) {
                        short4v pk;
                        for (int r = 0; r < 4; r++) {
                            float vv = acc[mb][nb][r] + bias;
                            pk[r] = (short)f2bf(vv);
                            psum[nb] += vv;
                        }
                        *(short4v*)&smem[col_l * 136 + waveM * 64 + mb * 16 + quad * 4] = pk;
                    }
                }
                const int hh = (n0 >> 6) + p;
                for (int nb = 0; nb < 4; nb++) {
                    float s = psum[nb];
                    s += __shfl_xor(s, 16, 64);
                    s += __shfl_xor(s, 32, 64);
                    if (quad == 0)
                        atomicAdd(&vmean[(nn * HEADS + hh) * DH + nb * 16 + l15], s);
                }
            }
            __syncthreads();
            const int hh = (n0 >> 6) + p;
            u16* drow = dst + ((size_t)(nn * HEADS + hh) * DH) * SEQ + ss0;
            for (int c2 = tid; c2 < 1024; c2 += 256) {
                int dl = c2 >> 4, tc = (c2 & 15) * 8;
                short8 vv = *(const short8*)&smem[dl * 136 + tc];
                *(short8*)(drow + (size_t)dl * SEQ + tc) = vv;
            }
            __syncthreads();
        }
    }
}

// ---------------------------------------------------------------------------
// Attention. R1-EXACT structure (measured best: 56.6us). Three structural
// variants all regressed: R2 regrid 80us (imbalance), R3 unroll 66us (+VALU),
// R10 dual-tile 65us (no chain overlap materialized; FETCH unchanged ->
// K/V already L2-resident). Flat grid 512; XCD k owns heads 4k..4k+3.
// Block processes complementary Q-tile pair (pr, 31-pr) -> uniform 33 iters.
// K/V staged via XOR-swizzled global_load_lds into double buffers; next tile
// issued right after the single per-iter barrier. S^T = K*Q^T. Softmax:
// scores pre-scaled by log2e -> bare exp2; no max-subtraction.
// Pad mask = ballot bitmask; causal only on diagonal tile; l==0 -> vmean
// (vmean buffer now holds SUM over t; divide by SEQ here).
// T5: s_setprio(1) around MFMA clusters.
// ---------------------------------------------------------------------------
__global__ __launch_bounds__(256) void attn_kernel(
    const u16* __restrict__ qh, const u16* __restrict__ kh, const u16* __restrict__ vt,
    const int* __restrict__ pad, const float* __restrict__ vmean,
    float* __restrict__ out)
{
    const int f = blockIdx.x;
    const int xcd = f & 7, jj = f >> 3;        // jj 0..63
    const int nh = xcd * 4 + (jj >> 4);
    const int pr = jj & 15;
    const int n = nh >> 4, h = nh & 15;
    const int tid  = threadIdx.x;
    const int wave = tid >> 6, lane = tid & 63;
    const int quad = lane >> 4, l15 = lane & 15;
    const int sw = l15 & 7;                    // frag-read swizzle key

    __shared__ __align__(16) u16 Ks[2][64 * 64];   // [t][d], XOR-swizzled chunks
    __shared__ __align__(16) u16 Vs[2][64 * 64];   // [d][t], XOR-swizzled chunks
    __shared__ __align__(16) u16 Ps[64 * 72];      // P [s][t], wave-private rows
    __shared__ u64 padb[32];

    // pad bitmask via wave ballots
    {
        const int* pp = pad + n * SEQ;
        for (int i = 0; i < 8; i++) {
            int seg = wave * 8 + i;
            u64 m = __ballot(pp[seg * 64 + lane] != 0);
            if (lane == 0) padb[seg] = m;
        }
    }

    const u16* qbase = qh + (size_t)nh * SEQ * DH;
    const u16* kbase = kh + (size_t)nh * SEQ * DH;
    const u16* vbase = vt + (size_t)nh * DH * SEQ;

    short8 ones;
    for (int i = 0; i < 8; i++) ones[i] = (short)0x3F80;   // bf16(1.0)
    float vm[4];
    for (int nd = 0; nd < 4; nd++)
        vm[nd] = vmean[nh * DH + nd * 16 + l15] * (1.f / (float)SEQ);

    const int lrow = lane >> 3;                 // 0..7 within 8-row slab
    const int gcol = ((lane & 7) ^ lrow) * 8;   // XOR-swizzled source chunk

    for (int half = 0; half < 2; half++) {
        const int sb = half ? (31 - pr) : pr;
        const int s0 = sb * 64;
        const int nt = sb + 1;
        const int srow = s0 + wave * 16 + l15;

        short8 qf[2];
        for (int ks = 0; ks < 2; ks++)
            qf[ks] = *(const short8*)(qbase + (size_t)srow * DH + ks * 32 + quad * 8);

        floatx4 oacc[4], lacc;
        for (int nd = 0; nd < 4; nd++) oacc[nd] = floatx4{0.f, 0.f, 0.f, 0.f};
        lacc = floatx4{0.f, 0.f, 0.f, 0.f};

        __syncthreads();   // half 0: padb visible; half 1: prev half's buffer reads done

        // stage tile 0 into buffer 0 (wave stages rows wave*16..wave*16+15)
        for (int j = 0; j < 2; j++) {
            int r8 = wave * 16 + j * 8;
            gll16(kbase + (size_t)(r8 + lrow) * DH + gcol, &Ks[0][r8 * 64]);
            gll16(vbase + (size_t)(r8 + lrow) * SEQ + gcol, &Vs[0][r8 * 64]);
        }

        for (int tb = 0; tb < nt; tb++) {
            const int cur = tb & 1;
            __syncthreads();       // drains own gll16s (issued a full iter ago) + buffer reuse

            if (tb + 1 < nt) {     // async prefetch of next tile into the other buffer
                const int t0n = (tb + 1) * 64;
                for (int j = 0; j < 2; j++) {
                    int r8 = wave * 16 + j * 8;
                    gll16(kbase + (size_t)(t0n + r8 + lrow) * DH + gcol, &Ks[1 - cur][r8 * 64]);
                    gll16(vbase + (size_t)(r8 + lrow) * SEQ + t0n + gcol, &Vs[1 - cur][r8 * 64]);
                }
            }

            const int t0 = tb * 64;
            const u64 w = padb[t0 >> 6];
            const bool diag = (tb == sb);

            // S^T = K Q^T : D[m=t][n=s]; lane r-quad consecutive in t
            floatx4 sc[4];
            for (int nb = 0; nb < 4; nb++) sc[nb] = floatx4{0.f, 0.f, 0.f, 0.f};
            __builtin_amdgcn_s_setprio(1);
            for (int ks = 0; ks < 2; ks++)
                for (int nb = 0; nb < 4; nb++) {
                    short8 kf = *(const short8*)&Ks[cur][(nb * 16 + l15) * 64 + ((ks * 4 + quad) ^ sw) * 8];
                    sc[nb] = __builtin_amdgcn_mfma_f32_16x16x32_bf16(kf, qf[ks], sc[nb], 0, 0, 0);
                }
            __builtin_amdgcn_s_setprio(0);

            // mask + exp2 + packed 8B write into Ps[s][t]
            for (int nb = 0; nb < 4; nb++) {
                short4v pk;
                for (int r = 0; r < 4; r++) {
                    int sh = nb * 16 + quad * 4 + r;        // t - t0
                    bool ok = ((w >> sh) & 1ull) != 0;
                    if (diag) ok = ok && (t0 + sh <= srow);
                    float p = ok ? __builtin_amdgcn_exp2f(sc[nb][r]) : 0.f;
                    pk[r] = (short)f2bf(p);
                }
                *(short4v*)&Ps[(wave * 16 + l15) * 72 + nb * 16 + quad * 4] = pk;
            }
            asm volatile("s_waitcnt lgkmcnt(0)" ::: "memory");   // wave-local Ps RAW

            // O += P V ; l += P @ ones
            __builtin_amdgcn_s_setprio(1);
            for (int ks = 0; ks < 2; ks++) {
                short8 pa = *(const short8*)&Ps[(wave * 16 + l15) * 72 + ks * 32 + quad * 8];
                for (int nd = 0; nd < 4; nd++) {
                    short8 vb = *(const short8*)&Vs[cur][(nd * 16 + l15) * 64 + ((ks * 4 + quad) ^ sw) * 8];
                    oacc[nd] = __builtin_amdgcn_mfma_f32_16x16x32_bf16(pa, vb, oacc[nd], 0, 0, 0);
                }
                lacc = __builtin_amdgcn_mfma_f32_16x16x32_bf16(pa, ones, lacc, 0, 0, 0);
            }
            __builtin_amdgcn_s_setprio(0);
        }

        // epilogue: lane holds O[s = s0+wave*16+quad*4+r][d = nd*16+l15]
        for (int r = 0; r < 4; r++) {
            float l = lacc[r];
            int s = s0 + wave * 16 + quad * 4 + r;
            float* orow = out + (size_t)(n * SEQ + s) * EMB + h * DH;
            if (l > 0.f) {
                float inv = 1.f / l;
                for (int nd = 0; nd < 4; nd++) orow[nd * 16 + l15] = oacc[nd][r] * inv;
            } else {
                for (int nd = 0; nd < 4; nd++) orow[nd * 16 + l15] = vm[nd];
            }
        }
    }
}

extern "C" void kernel_launch(void* const* d_in, const int* in_sizes, int n_in,
                              void* d_out, int out_size, void* d_ws, size_t ws_size,
                              hipStream_t stream)
{
    const float* qin = (const float*)d_in[0];
    const float* kin = (const float*)d_in[1];
    const float* vin = (const float*)d_in[2];
    const int*   pad = (const int*)d_in[3];
    // d_in[4] = subsq_mask (tril) — implemented analytically as t <= s
    const float* Wq = (const float*)d_in[5];
    const float* bq = (const float*)d_in[6];
    const float* Wk = (const float*)d_in[7];
    const float* bk = (const float*)d_in[8];
    const float* Wv = (const float*)d_in[9];
    const float* bv = (const float*)d_in[10];
    float* out = (float*)d_out;

    const size_t per = (size_t)NBAT * HEADS * SEQ * DH;  // 4M elements
    u16* qh = (u16*)d_ws;
    u16* kh = qh + per;
    u16* vt = kh + per;
    float* vmean = (float*)(vt + per);                   // 2048 floats (SUM over t)
    u16* xb = (u16*)(vmean + 2048);                      // 3 x 4M bf16
    u16* wb = xb + 3 * per;                              // 3 x 1M bf16

    cvt_kernel<<<dim3(512, 6), 256, 0, stream>>>(qin, kin, vin, Wq, Wk, Wv, xb, wb, vmean);
    proj_kernel<<<dim3(768), 256, 0, stream>>>(xb, wb, bq, bk, bv, qh, kh, vt, vmean);
    attn_kernel<<<dim3(512), 256, 0, stream>>>(qh, kh, vt, pad, vmean, out);
}